// Round 1
// baseline (727.467 us; speedup 1.0000x reference)
//
#include <hip/hip_runtime.h>
#include <hip/hip_bf16.h>

// NonLinearReadoutBlock: out = silu((x@W1)/16) masked-by-head @ W2/sqrt(128)
// N=500000, D_IN=256, D_HID=128, NUM_HEADS=4, D_OUT=4
//
// Strategy: bf16 MFMA (16x16x32) for x@W1 (memory-bound: 512MB x read),
// fp32 everywhere else. Mask exploited in epilogue via LDS compaction:
// wave w of each block owns cols [32w,32w+32) == head-block w exactly.

#define D_IN   256
#define D_HID  128
#define TILE_M 64
#define XPAD   264   // bf16 elems per LDS row: 256 + 8 pad -> conflict-free b128 reads
#define HPAD   36    // fp32 elems per kept-h row: 32 + 4 pad, keeps 16B alignment

typedef __attribute__((ext_vector_type(8))) short  short8;
typedef __attribute__((ext_vector_type(4))) float  float4v;

__device__ __forceinline__ unsigned short f2bf_rne(float f) {
    union { float f; unsigned int u; } cv; cv.f = f;
    unsigned int u = cv.u;
    return (unsigned short)((u + 0x7FFFu + ((u >> 16) & 1u)) >> 16);
}

// ---------------- prep: W1 [256][128] fp32 -> fragment-ordered bf16, *1/16 ----------------
// B-frag layout for mfma_f32_16x16x32_bf16: lane holds B[k][n], n=lane&15, k=(lane>>4)*8+j.
// W1p[((kt*8+nt)*64 + lane)*8 + j]  (kt = k/32, nt = n/16)
__global__ void prep_w1(const float* __restrict__ W1, unsigned short* __restrict__ W1p) {
    int idx = blockIdx.x * 256 + threadIdx.x;   // 0..32767
    int i = idx >> 7;     // k: 0..255
    int j = idx & 127;    // n: 0..127
    unsigned short b = f2bf_rne(W1[idx] * 0.0625f);   // fold 1/sqrt(256)
    int kt = i >> 5, q = (i >> 3) & 3, jj = i & 7;
    int nt = j >> 4, m = j & 15;
    int lane = q * 16 + m;
    W1p[(((kt * 8 + nt) * 64 + lane) << 3) + jj] = b;
}

// ---------------- main fused kernel ----------------
__global__ __launch_bounds__(256)
void readout_kernel(const float* __restrict__ x,
                    const unsigned short* __restrict__ W1p,
                    const float* __restrict__ W2,
                    const int* __restrict__ heads,
                    float* __restrict__ out, int nrows) {
    __shared__ unsigned short xs[TILE_M * XPAD];  // 33792 B
    __shared__ float hk[TILE_M * HPAD];           //  9216 B
    __shared__ int hs[TILE_M];                    //   256 B

    const int t    = threadIdx.x;
    const int row0 = blockIdx.x * TILE_M;

    // ---- stage heads ----
    if (t < TILE_M) {
        int gr = row0 + t;
        hs[t] = (gr < nrows) ? heads[gr] : 0;
    }

    // ---- stage x tile: fp32 global (coalesced float4) -> bf16 LDS ----
    #pragma unroll
    for (int it = 0; it < 16; ++it) {
        int idx = it * 256 + t;        // 0..4095
        int r   = idx >> 6;            // row in tile
        int cg  = idx & 63;            // float4 group (64 per row)
        float4v v = {0.f, 0.f, 0.f, 0.f};
        int gr = row0 + r;
        if (gr < nrows) v = *(const float4v*)(x + (size_t)gr * D_IN + cg * 4);
        ushort4 b;
        b.x = f2bf_rne(v[0]); b.y = f2bf_rne(v[1]);
        b.z = f2bf_rne(v[2]); b.w = f2bf_rne(v[3]);
        *(ushort4*)(&xs[r * XPAD + cg * 4]) = b;
    }
    __syncthreads();

    const int lane = t & 63;
    const int w    = t >> 6;     // wave id == head block this wave computes
    const int q    = lane >> 4;
    const int m    = lane & 15;

    float4v acc[4][2];
    #pragma unroll
    for (int rt = 0; rt < 4; ++rt)
        #pragma unroll
        for (int c = 0; c < 2; ++c) acc[rt][c] = (float4v){0.f, 0.f, 0.f, 0.f};

    // ---- K-loop: 8 steps of k=32 ----
    #pragma unroll
    for (int kt = 0; kt < 8; ++kt) {
        short8 a[4], b[2];
        #pragma unroll
        for (int rt = 0; rt < 4; ++rt) {
            // A[m][k]: m = lane&15 (row in rowtile), k = q*8 + j
            const unsigned short* p = &xs[(rt * 16 + m) * XPAD + kt * 32 + q * 8];
            a[rt] = *(const short8*)p;
        }
        #pragma unroll
        for (int c = 0; c < 2; ++c) {
            int nt = 2 * w + c;
            b[c] = *(const short8*)(W1p + (((kt * 8 + nt) * 64 + lane) << 3));
        }
        #pragma unroll
        for (int rt = 0; rt < 4; ++rt)
            #pragma unroll
            for (int c = 0; c < 2; ++c)
                acc[rt][c] = __builtin_amdgcn_mfma_f32_16x16x32_bf16(a[rt], b[c], acc[rt][c], 0, 0, 0);
    }

    // ---- epilogue phase 1: compact masked h into hk ----
    // D layout: col = lane&15 (+16*nt), row = q*4 + reg (+16*rt)
    #pragma unroll
    for (int rt = 0; rt < 4; ++rt)
        #pragma unroll
        for (int c = 0; c < 2; ++c)
            #pragma unroll
            for (int reg = 0; reg < 4; ++reg) {
                int row = rt * 16 + q * 4 + reg;
                if (hs[row] == w)
                    hk[row * HPAD + c * 16 + m] = acc[rt][c][reg];
            }
    __syncthreads();

    // ---- epilogue phase 2: silu + W2 over the 32 kept cols, 4 threads/row ----
    {
        int row  = t >> 2;
        int c8   = (t & 3) * 8;
        int head = hs[row];
        float4v o = {0.f, 0.f, 0.f, 0.f};
        float4v h0 = *(const float4v*)(&hk[row * HPAD + c8]);
        float4v h1 = *(const float4v*)(&hk[row * HPAD + c8 + 4]);
        #pragma unroll
        for (int jj = 0; jj < 8; ++jj) {
            float h = (jj < 4) ? h0[jj] : h1[jj - 4];
            float s = h / (1.0f + __expf(-h));          // silu, fp32
            int gj = head * 32 + c8 + jj;
            float4v w2 = *(const float4v*)(W2 + gj * 4);
            o += w2 * s;
        }
        #pragma unroll
        for (int d = 1; d < 4; d <<= 1) {
            #pragma unroll
            for (int e = 0; e < 4; ++e) o[e] += __shfl_xor(o[e], d, 64);
        }
        if ((t & 3) == 0) {
            int gr = row0 + row;
            if (gr < nrows) {
                const float sc = 0.08838834764831845f;  // 1/sqrt(128)
                float4v res = { o[0] * sc, o[1] * sc, o[2] * sc, o[3] * sc };
                *(float4v*)(out + (size_t)gr * 4) = res;
            }
        }
    }
}

extern "C" void kernel_launch(void* const* d_in, const int* in_sizes, int n_in,
                              void* d_out, int out_size, void* d_ws, size_t ws_size,
                              hipStream_t stream) {
    const float* x     = (const float*)d_in[0];
    const float* W1    = (const float*)d_in[1];
    const float* W2    = (const float*)d_in[2];
    const int*   heads = (const int*)d_in[3];
    float*       out   = (float*)d_out;
    unsigned short* W1p = (unsigned short*)d_ws;   // 64 KB fragment-ordered W1

    int nrows = in_sizes[0] / D_IN;

    prep_w1<<<128, 256, 0, stream>>>(W1, W1p);
    int nb = (nrows + TILE_M - 1) / TILE_M;
    readout_kernel<<<nb, 256, 0, stream>>>(x, W1p, W2, heads, out, nrows);
}

// Round 2
// 709.113 us; speedup vs baseline: 1.0259x; 1.0259x over previous
//
#include <hip/hip_runtime.h>
#include <hip/hip_bf16.h>

// NonLinearReadoutBlock: out = silu((x@W1)/16) masked-by-head @ W2/sqrt(128)
// N=500000, D_IN=256, D_HID=128, NUM_HEADS=4, D_OUT=4
//
// v2: barrier-free streaming. Each wave owns 32 rows x all 128 hidden cols.
// A-frags load directly from global x (coalesced 128B per m-group), cvt to
// bf16 in regs, MFMA 16x16x32. Head-mask select + silu + W2 + 16-lane
// shuffle reduce all in registers. ZERO LDS, ZERO __syncthreads.

#define D_IN   256
#define TILE_M 128   // 4 waves x 32 rows

typedef __attribute__((ext_vector_type(8))) short  short8;
typedef __attribute__((ext_vector_type(4))) float  float4v;
typedef __attribute__((ext_vector_type(4))) int    int4v;

__device__ __forceinline__ unsigned short f2bf_rne(float f) {
    union { float f; unsigned int u; } cv; cv.f = f;
    unsigned int u = cv.u;
    return (unsigned short)((u + 0x7FFFu + ((u >> 16) & 1u)) >> 16);
}

__device__ __forceinline__ short8 pack8(float4v lo, float4v hi) {
    short8 r;
    r[0] = (short)f2bf_rne(lo[0]); r[1] = (short)f2bf_rne(lo[1]);
    r[2] = (short)f2bf_rne(lo[2]); r[3] = (short)f2bf_rne(lo[3]);
    r[4] = (short)f2bf_rne(hi[0]); r[5] = (short)f2bf_rne(hi[1]);
    r[6] = (short)f2bf_rne(hi[2]); r[7] = (short)f2bf_rne(hi[3]);
    return r;
}

// ---------------- prep: W1 [256][128] fp32 -> fragment-ordered bf16, *1/16 ----------------
// B-frag layout for mfma_f32_16x16x32_bf16: lane holds B[k][n], n=lane&15, k=(lane>>4)*8+j.
// W1p[((kt*8+nt)*64 + lane)*8 + j]  (kt = k/32, nt = n/16)
__global__ void prep_w1(const float* __restrict__ W1, unsigned short* __restrict__ W1p) {
    int idx = blockIdx.x * 256 + threadIdx.x;   // 0..32767
    int i = idx >> 7;     // k: 0..255
    int j = idx & 127;    // n: 0..127
    unsigned short b = f2bf_rne(W1[idx] * 0.0625f);   // fold 1/sqrt(256)
    int kt = i >> 5, q = (i >> 3) & 3, jj = i & 7;
    int nt = j >> 4, mm = j & 15;
    int lane = q * 16 + mm;
    W1p[(((kt * 8 + nt) * 64 + lane) << 3) + jj] = b;
}

// ---------------- main fused kernel (no LDS, no barriers) ----------------
__global__ __launch_bounds__(256)
void readout_v2(const float* __restrict__ x,
                const unsigned short* __restrict__ W1p,
                const float* __restrict__ W2,
                const int* __restrict__ heads,
                float* __restrict__ out, int nrows) {
    const int t    = threadIdx.x;
    const int w    = t >> 6;          // wave id
    const int lane = t & 63;
    const int q    = lane >> 4;
    const int m    = lane & 15;
    const int rowbase = blockIdx.x * TILE_M + w * 32;   // wave's first row

    // A-frag row pointers (clamped; invalid rows masked at store)
    const int r0 = min(rowbase + m,      nrows - 1);
    const int r1 = min(rowbase + 16 + m, nrows - 1);
    const float* xr0 = x + (size_t)r0 * D_IN + q * 8;
    const float* xr1 = x + (size_t)r1 * D_IN + q * 8;
    const unsigned short* bbase = W1p + lane * 8;

    float4v acc[2][8];   // [rowtile][nt]
    #pragma unroll
    for (int rt = 0; rt < 2; ++rt)
        #pragma unroll
        for (int nt = 0; nt < 8; ++nt) acc[rt][nt] = (float4v){0.f, 0.f, 0.f, 0.f};

    // ---- K-loop: 8 steps of k=32, fully unrolled straight-line ----
    #pragma unroll
    for (int kt = 0; kt < 8; ++kt) {
        float4v a0lo = *(const float4v*)(xr0 + kt * 32);
        float4v a0hi = *(const float4v*)(xr0 + kt * 32 + 4);
        float4v a1lo = *(const float4v*)(xr1 + kt * 32);
        float4v a1hi = *(const float4v*)(xr1 + kt * 32 + 4);
        short8 b[8];
        #pragma unroll
        for (int nt = 0; nt < 8; ++nt)
            b[nt] = *(const short8*)(bbase + (kt * 8 + nt) * 512);
        short8 a0 = pack8(a0lo, a0hi);
        short8 a1 = pack8(a1lo, a1hi);
        #pragma unroll
        for (int nt = 0; nt < 8; ++nt) {
            acc[0][nt] = __builtin_amdgcn_mfma_f32_16x16x32_bf16(a0, b[nt], acc[0][nt], 0, 0, 0);
            acc[1][nt] = __builtin_amdgcn_mfma_f32_16x16x32_bf16(a1, b[nt], acc[1][nt], 0, 0, 0);
        }
    }

    // ---- epilogue: head select + silu + W2 + 16-lane reduce, all in regs ----
    // D layout: col = nt*16 + m, row (in 16) = q*4 + reg
    const float sc = 0.08838834764831845f;   // 1/sqrt(128)
    const bool full = (rowbase + 32) <= nrows;  // wave-uniform
    #pragma unroll
    for (int rt = 0; rt < 2; ++rt) {
        int4v hv;
        if (full) {
            hv = *(const int4v*)(heads + rowbase + rt * 16 + q * 4);
        } else {
            #pragma unroll
            for (int e = 0; e < 4; ++e)
                hv[e] = heads[min(rowbase + rt * 16 + q * 4 + e, nrows - 1)];
        }
        #pragma unroll
        for (int reg = 0; reg < 4; ++reg) {
            int h = hv[reg];
            float v0 = (h == 0) ? acc[rt][0][reg] : (h == 1) ? acc[rt][2][reg]
                     : (h == 2) ? acc[rt][4][reg] : acc[rt][6][reg];
            float v1 = (h == 0) ? acc[rt][1][reg] : (h == 1) ? acc[rt][3][reg]
                     : (h == 2) ? acc[rt][5][reg] : acc[rt][7][reg];
            float s0 = v0 / (1.0f + __expf(-v0));
            float s1 = v1 / (1.0f + __expf(-v1));
            float4v w2a = *(const float4v*)(W2 + (h * 32 + m) * 4);
            float4v w2b = *(const float4v*)(W2 + (h * 32 + 16 + m) * 4);
            float4v o = w2a * s0 + w2b * s1;
            #pragma unroll
            for (int d = 1; d < 16; d <<= 1) {
                o[0] += __shfl_xor(o[0], d, 64);
                o[1] += __shfl_xor(o[1], d, 64);
                o[2] += __shfl_xor(o[2], d, 64);
                o[3] += __shfl_xor(o[3], d, 64);
            }
            if (m == 0) {
                int gr = rowbase + rt * 16 + q * 4 + reg;
                if (gr < nrows) {
                    float4v res = { o[0] * sc, o[1] * sc, o[2] * sc, o[3] * sc };
                    *(float4v*)(out + (size_t)gr * 4) = res;
                }
            }
        }
    }
}

extern "C" void kernel_launch(void* const* d_in, const int* in_sizes, int n_in,
                              void* d_out, int out_size, void* d_ws, size_t ws_size,
                              hipStream_t stream) {
    const float* x     = (const float*)d_in[0];
    const float* W1    = (const float*)d_in[1];
    const float* W2    = (const float*)d_in[2];
    const int*   heads = (const int*)d_in[3];
    float*       out   = (float*)d_out;
    unsigned short* W1p = (unsigned short*)d_ws;   // 64 KB fragment-ordered W1

    int nrows = in_sizes[0] / D_IN;

    prep_w1<<<128, 256, 0, stream>>>(W1, W1p);
    int nb = (nrows + TILE_M - 1) / TILE_M;
    readout_v2<<<nb, 256, 0, stream>>>(x, W1p, W2, heads, out, nrows);
}